// Round 1
// baseline (249.031 us; speedup 1.0000x reference)
//
#include <hip/hip_runtime.h>
#include <stdint.h>

#define N_NODES 50000
#define F_IN 512
#define H_DIM 256
#define C_DIM 16

typedef __attribute__((ext_vector_type(8))) short short8;
typedef __attribute__((ext_vector_type(4))) float f32x4;
typedef __attribute__((ext_vector_type(4))) unsigned short us4;

__device__ inline float bf2f(unsigned short u) {
    return __uint_as_float(((uint32_t)u) << 16);
}
__device__ inline unsigned short f2bf(float f) {
    uint32_t u = __float_as_uint(f);
    u += 0x7FFFu + ((u >> 16) & 1u);   // round-to-nearest-even
    return (unsigned short)(u >> 16);
}
__device__ inline int eidx(const void* p, long long i, int is64) {
    return is64 ? (int)((const long long*)p)[i] : ((const int*)p)[i];
}

// ---------- graph build ----------

__global__ void detect_k(const void* ei, int* flag) {
    if (threadIdx.x == 0 && blockIdx.x == 0) {
        const uint32_t* w = (const uint32_t*)ei;
        int is64 = 1;
        for (int i = 1; i < 128; i += 2)
            if (w[i] != 0u) { is64 = 0; break; }
        *flag = is64;
    }
}

__global__ void hist_k(const void* ei, const int* flag, int* cnt, long long E) {
    long long e = (long long)blockIdx.x * 256 + threadIdx.x;
    if (e >= E) return;
    int d = eidx(ei, E + e, *flag);
    atomicAdd(&cnt[d], 1);
}

__global__ void dinv_k(const int* cnt, float* dinv) {
    int i = blockIdx.x * 256 + threadIdx.x;
    if (i < N_NODES) dinv[i] = rsqrtf((float)(cnt[i] + 1));
}

__global__ __launch_bounds__(512) void scan1_k(const int* cnt, int* rowoff, int* bsum, int n) {
    __shared__ int s[512];
    int t = threadIdx.x;
    int i = blockIdx.x * 512 + t;
    int v = (i < n) ? cnt[i] : 0;
    s[t] = v;
    __syncthreads();
    for (int off = 1; off < 512; off <<= 1) {
        int add = (t >= off) ? s[t - off] : 0;
        __syncthreads();
        s[t] += add;
        __syncthreads();
    }
    if (i < n) rowoff[i] = s[t] - v;    // exclusive within chunk
    if (t == 511) bsum[blockIdx.x] = s[511];
}

__global__ void scan2_k(int* bsum, int nb) {
    __shared__ int s[128];
    int t = threadIdx.x;
    int v = (t < nb) ? bsum[t] : 0;
    s[t] = v;
    __syncthreads();
    for (int off = 1; off < 128; off <<= 1) {
        int add = (t >= off) ? s[t - off] : 0;
        __syncthreads();
        s[t] += add;
        __syncthreads();
    }
    if (t < nb) bsum[t] = s[t] - v;     // exclusive block offsets
}

__global__ __launch_bounds__(512) void scan3_k(int* rowoff, const int* bsum, int n, int total) {
    int i = blockIdx.x * 512 + threadIdx.x;
    if (i < n) rowoff[i] += bsum[blockIdx.x];
    if (i == 0) rowoff[n] = total;
}

__global__ void scatter_k(const void* ei, const int* flag, const float* dinv,
                          const int* rowoff, int* cur, long long E, int2* colnorm) {
    long long e = (long long)blockIdx.x * 256 + threadIdx.x;
    if (e >= E) return;
    int is64 = *flag;
    int s = eidx(ei, e, is64);
    int d = eidx(ei, E + e, is64);
    int pos = rowoff[d] + atomicAdd(&cur[d], 1);
    float nrm = dinv[s] * dinv[d];
    int2 cn;
    cn.x = s;
    cn.y = __float_as_int(nrm);
    colnorm[pos] = cn;
}

// ---------- weight conversion (fp32 -> transposed bf16) ----------

__global__ void convW1_k(const float* w1, unsigned short* w1t) {
    int i = blockIdx.x * 256 + threadIdx.x;
    if (i >= F_IN * H_DIM) return;
    int k = i / H_DIM, n = i % H_DIM;
    w1t[n * F_IN + k] = f2bf(w1[i]);
}
__global__ void convW2_k(const float* w2, unsigned short* w2t) {
    int i = blockIdx.x * 256 + threadIdx.x;
    if (i >= H_DIM * C_DIM) return;
    int k = i / C_DIM, n = i % C_DIM;
    w2t[n * H_DIM + k] = f2bf(w2[i]);
}

// ---------- GEMM1: h1[50000x256] = bf16(x[50000x512] @ W1) via MFMA ----------
// block: 512 thr = 8 waves (2M x 4N); tile 128M x 256N x 32K; 16 K-steps.

__global__ __launch_bounds__(512) void gemm1_k(const float* __restrict__ x,
                                               const unsigned short* __restrict__ w1t,
                                               unsigned short* __restrict__ h1) {
    __shared__ __align__(16) unsigned short As[128][40];  // +8 pad: bank spread
    __shared__ __align__(16) unsigned short Bs[256][40];

    int t = threadIdx.x;
    int wv = t >> 6, lane = t & 63, lg = lane >> 4, lr = lane & 15;
    int wm = wv >> 2, wn = wv & 3;       // 2 x 4 wave grid

    f32x4 acc[4][4] = {};

    int ar = t >> 2;                      // 0..127  (A stage row)
    int ac = (t & 3) * 8;                 // 0/8/16/24 (A stage col)
    long long grow = (long long)blockIdx.x * 128 + ar;
    bool aok = grow < N_NODES;
    const float* xp = x + grow * F_IN + ac;

    int br = t >> 2;                      // B stage rows: br and br+128
    int bc = (t & 3) * 8;

    for (int ks = 0; ks < 16; ++ks) {
        int k0 = ks * 32;
        // global -> regs
        float av[8] = {0, 0, 0, 0, 0, 0, 0, 0};
        if (aok) {
            float4 v0 = *(const float4*)(xp + k0);
            float4 v1 = *(const float4*)(xp + k0 + 4);
            av[0] = v0.x; av[1] = v0.y; av[2] = v0.z; av[3] = v0.w;
            av[4] = v1.x; av[5] = v1.y; av[6] = v1.z; av[7] = v1.w;
        }
        short8 b0 = *(const short8*)(w1t + br * F_IN + k0 + bc);
        short8 b1v = *(const short8*)(w1t + (br + 128) * F_IN + k0 + bc);

        __syncthreads();                  // prev iter's LDS reads done
        short8 ap;
#pragma unroll
        for (int j = 0; j < 8; ++j) ap[j] = (short)f2bf(av[j]);
        *(short8*)&As[ar][ac] = ap;
        *(short8*)&Bs[br][bc] = b0;
        *(short8*)&Bs[br + 128][bc] = b1v;
        __syncthreads();

        short8 a[4], b[4];
#pragma unroll
        for (int mi = 0; mi < 4; ++mi)
            a[mi] = *(const short8*)&As[wm * 64 + mi * 16 + lr][lg * 8];
#pragma unroll
        for (int ni = 0; ni < 4; ++ni)
            b[ni] = *(const short8*)&Bs[wn * 64 + ni * 16 + lr][lg * 8];
#pragma unroll
        for (int mi = 0; mi < 4; ++mi)
#pragma unroll
            for (int ni = 0; ni < 4; ++ni)
                acc[mi][ni] = __builtin_amdgcn_mfma_f32_16x16x32_bf16(
                    a[mi], b[ni], acc[mi][ni], 0, 0, 0);
    }

    // epilogue: C layout col=lane&15, row=(lane>>4)*4+reg (m89-verified)
#pragma unroll
    for (int mi = 0; mi < 4; ++mi)
#pragma unroll
        for (int ni = 0; ni < 4; ++ni)
#pragma unroll
            for (int j = 0; j < 4; ++j) {
                long long row = (long long)blockIdx.x * 128 + wm * 64 + mi * 16 + lg * 4 + j;
                if (row < N_NODES)
                    h1[row * H_DIM + wn * 64 + ni * 16 + lr] = f2bf(acc[mi][ni][j]);
            }
}

// ---------- Aggregation layer 1: h1a = bf16(relu(A_norm @ h1 + b1)) ----------
// 1 wave per dst node; lane covers 4 features (8B bf16x4 loads).

__global__ __launch_bounds__(256) void agg1_k(const unsigned short* __restrict__ h1,
                                              const int* __restrict__ rowoff,
                                              const int2* __restrict__ colnorm,
                                              const float* __restrict__ dinv,
                                              const float* __restrict__ b1,
                                              unsigned short* __restrict__ h1a) {
    int wv = threadIdx.x >> 6, lane = threadIdx.x & 63;
    int node = blockIdx.x * 4 + wv;
    if (node >= N_NODES) return;
    int beg = rowoff[node], end = rowoff[node + 1];
    float ax = 0.f, ay = 0.f, az = 0.f, aw = 0.f;
    const unsigned short* base = h1 + lane * 4;
    int e = beg;
    for (; e + 1 < end; e += 2) {                   // 2-way ILP unroll
        int2 c0 = colnorm[e];
        int2 c1 = colnorm[e + 1];
        us4 v0 = *(const us4*)(base + (long long)c0.x * H_DIM);
        us4 v1 = *(const us4*)(base + (long long)c1.x * H_DIM);
        float n0 = __int_as_float(c0.y), n1 = __int_as_float(c1.y);
        ax += n0 * bf2f(v0.x) + n1 * bf2f(v1.x);
        ay += n0 * bf2f(v0.y) + n1 * bf2f(v1.y);
        az += n0 * bf2f(v0.z) + n1 * bf2f(v1.z);
        aw += n0 * bf2f(v0.w) + n1 * bf2f(v1.w);
    }
    if (e < end) {
        int2 c0 = colnorm[e];
        us4 v0 = *(const us4*)(base + (long long)c0.x * H_DIM);
        float n0 = __int_as_float(c0.y);
        ax += n0 * bf2f(v0.x);
        ay += n0 * bf2f(v0.y);
        az += n0 * bf2f(v0.z);
        aw += n0 * bf2f(v0.w);
    }
    // self loop: dinv[node]^2 * h1[node]
    float dn = dinv[node];
    float sn = dn * dn;
    us4 vs = *(const us4*)(base + (long long)node * H_DIM);
    ax += sn * bf2f(vs.x);
    ay += sn * bf2f(vs.y);
    az += sn * bf2f(vs.z);
    aw += sn * bf2f(vs.w);
    float4 bb = *(const float4*)(b1 + lane * 4);
    ax = fmaxf(ax + bb.x, 0.f);
    ay = fmaxf(ay + bb.y, 0.f);
    az = fmaxf(az + bb.z, 0.f);
    aw = fmaxf(aw + bb.w, 0.f);
    us4 o;
    o.x = f2bf(ax); o.y = f2bf(ay); o.z = f2bf(az); o.w = f2bf(aw);
    *(us4*)(h1a + (long long)node * H_DIM + lane * 4) = o;
}

// ---------- GEMM2: h2[50000x16] = h1a @ W2 (MFMA straight from global) ----------

__global__ __launch_bounds__(256) void gemm2_k(const unsigned short* __restrict__ h1a,
                                               const unsigned short* __restrict__ w2t,
                                               float* __restrict__ h2) {
    int t = threadIdx.x;
    int wv = t >> 6, lane = t & 63, lg = lane >> 4, lr = lane & 15;
    int rbase = blockIdx.x * 64 + wv * 16;
    int rr = rbase + lr;
    int rc = rr < N_NODES ? rr : N_NODES - 1;
    f32x4 acc = {0.f, 0.f, 0.f, 0.f};
#pragma unroll
    for (int ks = 0; ks < 8; ++ks) {
        short8 a = *(const short8*)(h1a + (long long)rc * H_DIM + ks * 32 + lg * 8);
        short8 b = *(const short8*)(w2t + lr * H_DIM + ks * 32 + lg * 8);
        acc = __builtin_amdgcn_mfma_f32_16x16x32_bf16(a, b, acc, 0, 0, 0);
    }
#pragma unroll
    for (int j = 0; j < 4; ++j) {
        int row = rbase + lg * 4 + j;
        if (row < N_NODES) h2[(long long)row * C_DIM + lr] = acc[j];
    }
}

// ---------- Aggregation layer 2: out = A_norm @ h2 + b2 (fp32) ----------
// 16 lanes per dst node (one per class).

__global__ __launch_bounds__(256) void agg2_k(const float* __restrict__ h2,
                                              const int* __restrict__ rowoff,
                                              const int2* __restrict__ colnorm,
                                              const float* __restrict__ dinv,
                                              const float* __restrict__ b2,
                                              float* __restrict__ out) {
    int g = threadIdx.x >> 4, c = threadIdx.x & 15;
    int node = blockIdx.x * 16 + g;
    if (node >= N_NODES) return;
    int beg = rowoff[node], end = rowoff[node + 1];
    float acc = 0.f;
    for (int e = beg; e < end; ++e) {
        int2 cn = colnorm[e];
        acc += __int_as_float(cn.y) * h2[(long long)cn.x * C_DIM + c];
    }
    float dn = dinv[node];
    acc += dn * dn * h2[(long long)node * C_DIM + c];
    out[(long long)node * C_DIM + c] = acc + b2[c];
}

// ---------- launch ----------

extern "C" void kernel_launch(void* const* d_in, const int* in_sizes, int n_in,
                              void* d_out, int out_size, void* d_ws, size_t ws_size,
                              hipStream_t stream) {
    const float* x  = (const float*)d_in[0];
    const void*  ei = d_in[1];
    const float* W1 = (const float*)d_in[2];
    const float* b1 = (const float*)d_in[3];
    const float* W2 = (const float*)d_in[4];
    const float* b2 = (const float*)d_in[5];
    float* out = (float*)d_out;
    long long E = (long long)in_sizes[1] / 2;

    char* w = (char*)d_ws;
    auto alloc = [&](size_t bytes) -> char* {
        char* p = w;
        w += (bytes + 255) & ~(size_t)255;
        return p;
    };
    int*   flag    = (int*)   alloc(4);
    int*   cnt     = (int*)   alloc((size_t)N_NODES * 4);
    int*   cur     = (int*)   alloc((size_t)N_NODES * 4);
    float* dinv    = (float*) alloc((size_t)N_NODES * 4);
    int*   rowoff  = (int*)   alloc((size_t)(N_NODES + 1) * 4);
    int*   bsum    = (int*)   alloc(512 * 4);
    int2*  colnorm = (int2*)  alloc((size_t)E * 8);
    unsigned short* w1t = (unsigned short*)alloc((size_t)H_DIM * F_IN * 2);
    unsigned short* w2t = (unsigned short*)alloc((size_t)C_DIM * H_DIM * 2);
    unsigned short* h1  = (unsigned short*)alloc((size_t)N_NODES * H_DIM * 2);
    unsigned short* h1a = (unsigned short*)alloc((size_t)N_NODES * H_DIM * 2);
    float* h2 = (float*)alloc((size_t)N_NODES * C_DIM * 4);

    hipMemsetAsync(cnt, 0, (size_t)N_NODES * 4, stream);
    hipMemsetAsync(cur, 0, (size_t)N_NODES * 4, stream);
    detect_k<<<1, 64, 0, stream>>>(ei, flag);
    convW1_k<<<(F_IN * H_DIM + 255) / 256, 256, 0, stream>>>(W1, w1t);
    convW2_k<<<(H_DIM * C_DIM + 255) / 256, 256, 0, stream>>>(W2, w2t);

    int egrid = (int)((E + 255) / 256);
    hist_k<<<egrid, 256, 0, stream>>>(ei, flag, cnt, E);
    dinv_k<<<(N_NODES + 255) / 256, 256, 0, stream>>>(cnt, dinv);
    int sgrid = (N_NODES + 511) / 512;   // 98 (<=128 for scan2)
    scan1_k<<<sgrid, 512, 0, stream>>>(cnt, rowoff, bsum, N_NODES);
    scan2_k<<<1, 128, 0, stream>>>(bsum, sgrid);
    scan3_k<<<sgrid, 512, 0, stream>>>(rowoff, bsum, N_NODES, (int)E);
    scatter_k<<<egrid, 256, 0, stream>>>(ei, flag, dinv, rowoff, cur, E, colnorm);

    gemm1_k<<<(N_NODES + 127) / 128, 512, 0, stream>>>(x, w1t, h1);
    agg1_k<<<(N_NODES + 3) / 4, 256, 0, stream>>>(h1, rowoff, colnorm, dinv, b1, h1a);
    gemm2_k<<<(N_NODES + 63) / 64, 256, 0, stream>>>(h1a, w2t, h2);
    agg2_k<<<(N_NODES + 15) / 16, 256, 0, stream>>>(h2, rowoff, colnorm, dinv, b2, out);
}

// Round 2
// 235.975 us; speedup vs baseline: 1.0553x; 1.0553x over previous
//
#include <hip/hip_runtime.h>
#include <stdint.h>

#define N_NODES 50000
#define F_IN 512
#define H_DIM 256
#define C_DIM 16

typedef __attribute__((ext_vector_type(8))) short short8;
typedef __attribute__((ext_vector_type(4))) float f32x4;
typedef __attribute__((ext_vector_type(4))) unsigned short us4;

__device__ inline float bf2f(unsigned short u) {
    return __uint_as_float(((uint32_t)u) << 16);
}
__device__ inline unsigned short f2bf(float f) {
    uint32_t u = __float_as_uint(f);
    u += 0x7FFFu + ((u >> 16) & 1u);   // round-to-nearest-even
    return (unsigned short)(u >> 16);
}
__device__ inline int eidx(const void* p, long long i, int is64) {
    return is64 ? (int)((const long long*)p)[i] : ((const int*)p)[i];
}

// ---------- fused prep: dtype detect + W1/W2 transpose-convert ----------

__global__ void prep_k(const void* ei, int* flag,
                       const float* w1, unsigned short* w1t,
                       const float* w2, unsigned short* w2t) {
    int i = blockIdx.x * 256 + threadIdx.x;
    if (i == 0) {
        const uint32_t* w = (const uint32_t*)ei;
        int is64 = 1;
        for (int j = 1; j < 128; j += 2)
            if (w[j] != 0u) { is64 = 0; break; }
        *flag = is64;
    }
    if (i < F_IN * H_DIM) {
        int k = i / H_DIM, n = i % H_DIM;
        w1t[n * F_IN + k] = f2bf(w1[i]);
    }
    if (i < H_DIM * C_DIM) {
        int k = i / C_DIM, n = i % C_DIM;
        w2t[n * H_DIM + k] = f2bf(w2[i]);
    }
}

// ---------- graph build ----------

__global__ void hist_k(const void* ei, const int* flag, int* cnt, long long E) {
    long long e = (long long)blockIdx.x * 256 + threadIdx.x;
    if (e >= E) return;
    int d = eidx(ei, E + e, *flag);
    atomicAdd(&cnt[d], 1);
}

__global__ __launch_bounds__(512) void scan1_k(const int* cnt, int* rowoff, int* bsum,
                                               float* dinv, int n) {
    __shared__ int s[512];
    int t = threadIdx.x;
    int i = blockIdx.x * 512 + t;
    int v = (i < n) ? cnt[i] : 0;
    s[t] = v;
    __syncthreads();
    for (int off = 1; off < 512; off <<= 1) {
        int add = (t >= off) ? s[t - off] : 0;
        __syncthreads();
        s[t] += add;
        __syncthreads();
    }
    if (i < n) {
        rowoff[i] = s[t] - v;                 // exclusive within chunk
        dinv[i] = rsqrtf((float)(v + 1));     // +1 self loop
    }
    if (t == 511) bsum[blockIdx.x] = s[511];
}

__global__ void scan2_k(int* bsum, int nb) {
    __shared__ int s[128];
    int t = threadIdx.x;
    int v = (t < nb) ? bsum[t] : 0;
    s[t] = v;
    __syncthreads();
    for (int off = 1; off < 128; off <<= 1) {
        int add = (t >= off) ? s[t - off] : 0;
        __syncthreads();
        s[t] += add;
        __syncthreads();
    }
    if (t < nb) bsum[t] = s[t] - v;     // exclusive block offsets
}

__global__ __launch_bounds__(512) void scan3_k(int* rowoff, const int* bsum, int n, int total) {
    int i = blockIdx.x * 512 + threadIdx.x;
    if (i < n) rowoff[i] += bsum[blockIdx.x];
    if (i == 0) rowoff[n] = total;
}

__global__ void scatter_k(const void* ei, const int* flag, const float* dinv,
                          const int* rowoff, int* cur, long long E, int2* colnorm) {
    long long e = (long long)blockIdx.x * 256 + threadIdx.x;
    if (e >= E) return;
    int is64 = *flag;
    int s = eidx(ei, e, is64);
    int d = eidx(ei, E + e, is64);
    int pos = rowoff[d] + atomicAdd(&cur[d], 1);
    float nrm = dinv[s] * dinv[d];
    int2 cn;
    cn.x = s;
    cn.y = __float_as_int(nrm);
    colnorm[pos] = cn;
}

// ---------- GEMM1: h1[50000x256] = bf16(x @ W1) via MFMA ----------
// 64M x 256N tile, 4 waves (1M x 4N), BK=32, 16 K-steps, grid 782.
// A (fp32->bf16) staged in double-buffered LDS; B read per-wave from L2.
// 2-deep A prefetch; barrier = lgkmcnt(0)+s_barrier so vmcnt stays counted.

#define GBAR() do { asm volatile("s_waitcnt lgkmcnt(0)" ::: "memory"); \
                    __builtin_amdgcn_s_barrier(); } while (0)

__global__ __launch_bounds__(256) void gemm1_k(const float* __restrict__ x,
                                               const unsigned short* __restrict__ w1t,
                                               unsigned short* __restrict__ h1) {
    __shared__ __align__(16) unsigned short As[2][64][40];  // 80B rows: 16B-aligned, bank-spread

    const int t = threadIdx.x;
    const int wn = t >> 6, lane = t & 63;
    const int lg = lane >> 4, lr = lane & 15;

    f32x4 acc[4][4] = {};

    const int ar = t >> 2;              // 0..63  A stage row
    const int ac = (t & 3) * 8;         // 0/8/16/24 A stage col
    const long long grow = (long long)blockIdx.x * 64 + ar;
    const bool aok = grow < N_NODES;
    const float* xp = x + (aok ? grow * (long long)F_IN + ac : 0);
    const unsigned short* wp = w1t + (wn * 64 + lr) * F_IN + lg * 8;

    float bufA[8], bufB[8];

#define LOADA(ks, buf)                                                        \
    do { if (aok) {                                                           \
        float4 u0 = *(const float4*)(xp + (ks) * 32);                         \
        float4 u1 = *(const float4*)(xp + (ks) * 32 + 4);                     \
        buf[0] = u0.x; buf[1] = u0.y; buf[2] = u0.z; buf[3] = u0.w;           \
        buf[4] = u1.x; buf[5] = u1.y; buf[6] = u1.z; buf[7] = u1.w;           \
    } else { _Pragma("unroll") for (int j = 0; j < 8; ++j) buf[j] = 0.f; } } while (0)

#define STOREA(b, buf)                                                        \
    do { short8 ap;                                                           \
        _Pragma("unroll") for (int j = 0; j < 8; ++j) ap[j] = (short)f2bf(buf[j]); \
        *(short8*)&As[b][ar][ac] = ap; } while (0)

#define COMPUTE(b, ks)                                                        \
    do { short8 bfr[4], afr[4];                                               \
        _Pragma("unroll") for (int ni = 0; ni < 4; ++ni)                      \
            bfr[ni] = *(const short8*)(wp + ni * 16 * F_IN + (ks) * 32);      \
        _Pragma("unroll") for (int mi = 0; mi < 4; ++mi)                      \
            afr[mi] = *(const short8*)&As[b][mi * 16 + lr][lg * 8];           \
        _Pragma("unroll") for (int mi = 0; mi < 4; ++mi)                      \
            _Pragma("unroll") for (int ni = 0; ni < 4; ++ni)                  \
                acc[mi][ni] = __builtin_amdgcn_mfma_f32_16x16x32_bf16(        \
                    afr[mi], bfr[ni], acc[mi][ni], 0, 0, 0);                  \
    } while (0)

    // prologue: stage tile0; issue tile1 loads (stay in flight)
    LOADA(0, bufA);
    STOREA(0, bufA);
    LOADA(1, bufB);
    GBAR();

    for (int kk = 0; kk < 8; ++kk) {
        const int ks = kk * 2;
        // even step: compute LDS buf0(tile ks); prefetch tile ks+2; stage tile ks+1
        if (ks + 2 < 16) LOADA(ks + 2, bufA);
        COMPUTE(0, ks);
        STOREA(1, bufB);            // waits only on bufB's own loads (counted vmcnt)
        GBAR();
        // odd step: compute LDS buf1(tile ks+1); prefetch tile ks+3; stage tile ks+2
        if (ks + 3 < 16) LOADA(ks + 3, bufB);
        COMPUTE(1, ks + 1);
        if (ks + 2 < 16) STOREA(0, bufA);
        GBAR();
    }

    // epilogue: C layout col=lane&15, row=(lane>>4)*4+reg
#pragma unroll
    for (int mi = 0; mi < 4; ++mi)
#pragma unroll
        for (int ni = 0; ni < 4; ++ni)
#pragma unroll
            for (int j = 0; j < 4; ++j) {
                long long row = (long long)blockIdx.x * 64 + mi * 16 + lg * 4 + j;
                if (row < N_NODES)
                    h1[row * H_DIM + wn * 64 + ni * 16 + lr] = f2bf(acc[mi][ni][j]);
            }
#undef LOADA
#undef STOREA
#undef COMPUTE
}

// ---------- Aggregation layer 1: h1a = bf16(relu(A_norm @ h1 + b1)) ----------
// 1 wave per dst node; lane covers 4 features; 4-way ILP gather.

__global__ __launch_bounds__(256) void agg1_k(const unsigned short* __restrict__ h1,
                                              const int* __restrict__ rowoff,
                                              const int2* __restrict__ colnorm,
                                              const float* __restrict__ dinv,
                                              const float* __restrict__ b1,
                                              unsigned short* __restrict__ h1a) {
    int wv = threadIdx.x >> 6, lane = threadIdx.x & 63;
    int node = blockIdx.x * 4 + wv;
    if (node >= N_NODES) return;
    int beg = rowoff[node], end = rowoff[node + 1];
    float ax = 0.f, ay = 0.f, az = 0.f, aw = 0.f;
    const unsigned short* base = h1 + lane * 4;
    int e = beg;
    for (; e + 3 < end; e += 4) {                   // 4-way ILP
        int2 c0 = colnorm[e];
        int2 c1 = colnorm[e + 1];
        int2 c2 = colnorm[e + 2];
        int2 c3 = colnorm[e + 3];
        us4 v0 = *(const us4*)(base + (long long)c0.x * H_DIM);
        us4 v1 = *(const us4*)(base + (long long)c1.x * H_DIM);
        us4 v2 = *(const us4*)(base + (long long)c2.x * H_DIM);
        us4 v3 = *(const us4*)(base + (long long)c3.x * H_DIM);
        float n0 = __int_as_float(c0.y), n1 = __int_as_float(c1.y);
        float n2 = __int_as_float(c2.y), n3 = __int_as_float(c3.y);
        ax += n0 * bf2f(v0.x) + n1 * bf2f(v1.x) + n2 * bf2f(v2.x) + n3 * bf2f(v3.x);
        ay += n0 * bf2f(v0.y) + n1 * bf2f(v1.y) + n2 * bf2f(v2.y) + n3 * bf2f(v3.y);
        az += n0 * bf2f(v0.z) + n1 * bf2f(v1.z) + n2 * bf2f(v2.z) + n3 * bf2f(v3.z);
        aw += n0 * bf2f(v0.w) + n1 * bf2f(v1.w) + n2 * bf2f(v2.w) + n3 * bf2f(v3.w);
    }
    for (; e < end; ++e) {
        int2 c0 = colnorm[e];
        us4 v0 = *(const us4*)(base + (long long)c0.x * H_DIM);
        float n0 = __int_as_float(c0.y);
        ax += n0 * bf2f(v0.x);
        ay += n0 * bf2f(v0.y);
        az += n0 * bf2f(v0.z);
        aw += n0 * bf2f(v0.w);
    }
    // self loop: dinv[node]^2 * h1[node]
    float dn = dinv[node];
    float sn = dn * dn;
    us4 vs = *(const us4*)(base + (long long)node * H_DIM);
    ax += sn * bf2f(vs.x);
    ay += sn * bf2f(vs.y);
    az += sn * bf2f(vs.z);
    aw += sn * bf2f(vs.w);
    float4 bb = *(const float4*)(b1 + lane * 4);
    ax = fmaxf(ax + bb.x, 0.f);
    ay = fmaxf(ay + bb.y, 0.f);
    az = fmaxf(az + bb.z, 0.f);
    aw = fmaxf(aw + bb.w, 0.f);
    us4 o;
    o.x = f2bf(ax); o.y = f2bf(ay); o.z = f2bf(az); o.w = f2bf(aw);
    *(us4*)(h1a + (long long)node * H_DIM + lane * 4) = o;
}

// ---------- GEMM2: h2[50000x16] = h1a @ W2 (MFMA straight from global) ----------

__global__ __launch_bounds__(256) void gemm2_k(const unsigned short* __restrict__ h1a,
                                               const unsigned short* __restrict__ w2t,
                                               float* __restrict__ h2) {
    int t = threadIdx.x;
    int wv = t >> 6, lane = t & 63, lg = lane >> 4, lr = lane & 15;
    int rbase = blockIdx.x * 64 + wv * 16;
    int rr = rbase + lr;
    int rc = rr < N_NODES ? rr : N_NODES - 1;
    f32x4 acc = {0.f, 0.f, 0.f, 0.f};
#pragma unroll
    for (int ks = 0; ks < 8; ++ks) {
        short8 a = *(const short8*)(h1a + (long long)rc * H_DIM + ks * 32 + lg * 8);
        short8 b = *(const short8*)(w2t + lr * H_DIM + ks * 32 + lg * 8);
        acc = __builtin_amdgcn_mfma_f32_16x16x32_bf16(a, b, acc, 0, 0, 0);
    }
#pragma unroll
    for (int j = 0; j < 4; ++j) {
        int row = rbase + lg * 4 + j;
        if (row < N_NODES) h2[(long long)row * C_DIM + lr] = acc[j];
    }
}

// ---------- Aggregation layer 2: out = A_norm @ h2 + b2 (fp32) ----------

__global__ __launch_bounds__(256) void agg2_k(const float* __restrict__ h2,
                                              const int* __restrict__ rowoff,
                                              const int2* __restrict__ colnorm,
                                              const float* __restrict__ dinv,
                                              const float* __restrict__ b2,
                                              float* __restrict__ out) {
    int g = threadIdx.x >> 4, c = threadIdx.x & 15;
    int node = blockIdx.x * 16 + g;
    if (node >= N_NODES) return;
    int beg = rowoff[node], end = rowoff[node + 1];
    float acc = 0.f;
    int e = beg;
    for (; e + 1 < end; e += 2) {
        int2 cn0 = colnorm[e];
        int2 cn1 = colnorm[e + 1];
        acc += __int_as_float(cn0.y) * h2[(long long)cn0.x * C_DIM + c]
             + __int_as_float(cn1.y) * h2[(long long)cn1.x * C_DIM + c];
    }
    if (e < end) {
        int2 cn = colnorm[e];
        acc += __int_as_float(cn.y) * h2[(long long)cn.x * C_DIM + c];
    }
    float dn = dinv[node];
    acc += dn * dn * h2[(long long)node * C_DIM + c];
    out[(long long)node * C_DIM + c] = acc + b2[c];
}

// ---------- launch ----------

extern "C" void kernel_launch(void* const* d_in, const int* in_sizes, int n_in,
                              void* d_out, int out_size, void* d_ws, size_t ws_size,
                              hipStream_t stream) {
    const float* x  = (const float*)d_in[0];
    const void*  ei = d_in[1];
    const float* W1 = (const float*)d_in[2];
    const float* b1 = (const float*)d_in[3];
    const float* W2 = (const float*)d_in[4];
    const float* b2 = (const float*)d_in[5];
    float* out = (float*)d_out;
    long long E = (long long)in_sizes[1] / 2;

    char* w = (char*)d_ws;
    auto alloc = [&](size_t bytes) -> char* {
        char* p = w;
        w += (bytes + 255) & ~(size_t)255;
        return p;
    };
    int*   flag    = (int*)   alloc(4);
    int*   cnt     = (int*)   alloc((size_t)N_NODES * 4);
    int*   cur     = (int*)   alloc((size_t)N_NODES * 4);
    float* dinv    = (float*) alloc((size_t)N_NODES * 4);
    int*   rowoff  = (int*)   alloc((size_t)(N_NODES + 1) * 4);
    int*   bsum    = (int*)   alloc(512 * 4);
    int2*  colnorm = (int2*)  alloc((size_t)E * 8);
    unsigned short* w1t = (unsigned short*)alloc((size_t)H_DIM * F_IN * 2);
    unsigned short* w2t = (unsigned short*)alloc((size_t)C_DIM * H_DIM * 2);
    unsigned short* h1  = (unsigned short*)alloc((size_t)N_NODES * H_DIM * 2);
    unsigned short* h1a = (unsigned short*)alloc((size_t)N_NODES * H_DIM * 2);
    float* h2 = (float*)alloc((size_t)N_NODES * C_DIM * 4);

    hipMemsetAsync(cnt, 0, (size_t)N_NODES * 4, stream);
    hipMemsetAsync(cur, 0, (size_t)N_NODES * 4, stream);
    prep_k<<<(F_IN * H_DIM + 255) / 256, 256, 0, stream>>>(ei, flag, W1, w1t, W2, w2t);

    int egrid = (int)((E + 255) / 256);
    hist_k<<<egrid, 256, 0, stream>>>(ei, flag, cnt, E);
    int sgrid = (N_NODES + 511) / 512;   // 98 (<=128 for scan2)
    scan1_k<<<sgrid, 512, 0, stream>>>(cnt, rowoff, bsum, dinv, N_NODES);
    scan2_k<<<1, 128, 0, stream>>>(bsum, sgrid);
    scan3_k<<<sgrid, 512, 0, stream>>>(rowoff, bsum, N_NODES, (int)E);
    scatter_k<<<egrid, 256, 0, stream>>>(ei, flag, dinv, rowoff, cur, E, colnorm);

    gemm1_k<<<(N_NODES + 63) / 64, 256, 0, stream>>>(x, w1t, h1);
    agg1_k<<<(N_NODES + 3) / 4, 256, 0, stream>>>(h1, rowoff, colnorm, dinv, b1, h1a);
    gemm2_k<<<(N_NODES + 63) / 64, 256, 0, stream>>>(h1a, w2t, h2);
    agg2_k<<<(N_NODES + 15) / 16, 256, 0, stream>>>(h2, rowoff, colnorm, dinv, b2, out);
}